// Round 16
// baseline (239.383 us; speedup 1.0000x reference)
//
#include <hip/hip_runtime.h>
#include <hip/hip_fp16.h>

// MessagePassing: 10 iterations of 3x3 per-pixel-weighted smoothing.
//   input [8,64,128,128] f32, weight [8,9,128,128] f32 -> out [8,64,128,128] f32
// R16 = R15 (best: 92.5us) with b's volatile loads relaxed.
// R15 evidence: a (f32->fp16cells) ~35us; b (fp16cells->f32) 53.5us clean but
// slow -- volatile forces L1-bypass + per-load ordering waits, serializing the
// B0 load phase. The R14 hoist-spill needed only `#pragma unroll 1` to die
// (no unrolled 2nd iteration = nothing to hoist across the step loop), so:
// plain uint4 load + unroll 1 + sched_barrier(0) after the load phase.
// Kill-check: if b's WRITE >> 33MB the acc spill returned -> revert to R15.

#define NB    8
#define CC    64
#define HH    128
#define WW    128
#define TAPS  9
#define PLANE (HH * WW)

#define CORE   16            // output tile rows per kernel
#define HALO5  5
#define RROWS  26            // CORE + 2*HALO5
#define RSTR4  129           // x-buffer row stride in cells (uint4)
#define NTH    832           // 26 rows * 32 strips, 13 waves
#define NSTEP  5
#define CGRP   16            // channels per block
#define CSUB   8             // channels per chunk (fp16 x8 in uint4 cell)
#define WROWS  24            // weight rows resident (region rows 1..24)
#define WCELLS (WROWS * TAPS * 32)   // half4 (uint2) cells = 6912 (55,296 B)

#define PERM4(J) ((((J) & 3) << 5) | ((J) >> 2))   // bijective on 0..127

__device__ __forceinline__ float4 fma4(const float4 a, const float s, const float4 c) {
    return make_float4(fmaf(a.x, s, c.x), fmaf(a.y, s, c.y),
                       fmaf(a.z, s, c.z), fmaf(a.w, s, c.w));
}

__device__ __forceinline__ float4 cvt_lo(const uint4 v) {   // ch0-3
    const float2 a = __half22float2(*reinterpret_cast<const __half2*>(&v.x));
    const float2 b = __half22float2(*reinterpret_cast<const __half2*>(&v.y));
    return make_float4(a.x, a.y, b.x, b.y);
}
__device__ __forceinline__ float4 cvt_hi(const uint4 v) {   // ch4-7
    const float2 a = __half22float2(*reinterpret_cast<const __half2*>(&v.z));
    const float2 b = __half22float2(*reinterpret_cast<const __half2*>(&v.w));
    return make_float4(a.x, a.y, b.x, b.y);
}
__device__ __forceinline__ unsigned pack2(float a, float b) {
    __half2 h = __floats2half2_rn(a, b);
    return *reinterpret_cast<unsigned*>(&h);
}

// Normalize taps, store fp16: layout [n][9][128][32] uint2 (half4 cells).
__global__ __launch_bounds__(256) void mp_norm_kernel(const float* __restrict__ w,
                                                      uint2* __restrict__ nwh) {
    int tid = blockIdx.x * 256 + threadIdx.x;       // 32768 threads
    int wg = tid & 31;
    int h  = (tid >> 5) & 127;
    int n  = tid >> 12;
    int base = n * TAPS * PLANE + h * WW + wg * 4;
    float4 t[TAPS];
    float sx = 1e-5f, sy = 1e-5f, sz = 1e-5f, sw = 1e-5f;
#pragma unroll
    for (int k = 0; k < TAPS; ++k) {
        t[k] = *reinterpret_cast<const float4*>(w + base + k * PLANE);
        sx += t[k].x; sy += t[k].y; sz += t[k].z; sw += t[k].w;
    }
    float rx = 1.0f / sx, ry = 1.0f / sy, rz = 1.0f / sz, rw = 1.0f / sw;
#pragma unroll
    for (int k = 0; k < TAPS; ++k) {
        uint2 v;
        v.x = pack2(t[k].x * rx, t[k].y * ry);
        v.y = pack2(t[k].z * rz, t[k].w * rw);
        nwh[((n * TAPS + k) * HH + h) * 32 + wg] = v;
    }
}

// Shared pieces (macros so both kernels get byte-identical step loops without
// any shared template/function regalloc context).
#define FUSED_PROLOGUE                                                          \
    __shared__ uint4 bufA[RROWS * RSTR4];                                       \
    __shared__ uint4 bufB[RROWS * RSTR4];                                       \
    __shared__ uint2 wlds[WCELLS];                                              \
    const int bid = blockIdx.x;                                                 \
    const int n   = bid & 7;                                                    \
    const int ht  = (bid >> 3) & 7;                                             \
    const int cg  = bid >> 6;                                                   \
    const int tr0 = ht * CORE;                                                  \
    const int cb  = cg * CGRP;                                                  \
    const int t   = threadIdx.x;                                                \
    const int row = t >> 5;                                                     \
    const int s   = t & 31;                                                     \
    {                                                                           \
        const uint2* nwb = nwh + (size_t)n * TAPS * (PLANE / 4);                \
        for (int idx = t; idx < WCELLS; idx += NTH) {                           \
            const int wrow = idx / (TAPS * 32);                                 \
            const int rem  = idx - wrow * (TAPS * 32);                          \
            const int k    = rem >> 5;                                          \
            const int ss   = rem & 31;                                          \
            const int gr   = tr0 - (HALO5 - 1) + wrow;                          \
            uint2 v = make_uint2(0u, 0u);                                       \
            if (gr >= 0 && gr < HH)                                             \
                v = nwb[(k * HH + gr) * 32 + ss];                               \
            wlds[idx] = v;                                                      \
        }                                                                       \
    }                                                                           \
    const uint4 zc = make_uint4(0u, 0u, 0u, 0u);                                \
    const float4 z = make_float4(0.f, 0.f, 0.f, 0.f);

#define FUSED_STEPS                                                             \
        uint4* pin  = bufA;                                                     \
        uint4* pout = bufB;                                                     \
        for (int st = 0; st < NSTEP; ++st) {                                    \
            const int lo = st + 1;                                              \
            const int hi = 24 - st;                                             \
            if (row >= lo && row <= hi) {                                       \
                int wb = (row - 1) * (TAPS * 32) + s;                           \
                asm volatile("" : "+v"(wb));                                    \
                float4 aL0 = z, aL1 = z, aL2 = z, aL3 = z;                      \
                float4 aH0 = z, aH1 = z, aH2 = z, aH3 = z;                      \
                _Pragma("unroll")                                               \
                for (int di = 0; di < 3; ++di) {                                \
                    const uint4* rp = pin + (row - 1 + di) * RSTR4;             \
                    uint4 x[6];                                                 \
                    x[0] = (s > 0) ? rp[96 + s - 1] : zc;                       \
                    x[1] = rp[s];                                               \
                    x[2] = rp[32 + s];                                          \
                    x[3] = rp[64 + s];                                          \
                    x[4] = rp[96 + s];                                          \
                    x[5] = (s < 31) ? rp[s + 1] : zc;                           \
                    _Pragma("unroll")                                           \
                    for (int dj = 0; dj < 3; ++dj) {                            \
                        const int k = di * 3 + dj;                              \
                        const uint2 wv = wlds[wb + k * 32];                     \
                        const float2 w01 = __half22float2(*reinterpret_cast<const __half2*>(&wv.x)); \
                        const float2 w23 = __half22float2(*reinterpret_cast<const __half2*>(&wv.y)); \
                        aL0 = fma4(cvt_lo(x[0 + dj]), w01.x, aL0);              \
                        aH0 = fma4(cvt_hi(x[0 + dj]), w01.x, aH0);              \
                        aL1 = fma4(cvt_lo(x[1 + dj]), w01.y, aL1);              \
                        aH1 = fma4(cvt_hi(x[1 + dj]), w01.y, aH1);              \
                        aL2 = fma4(cvt_lo(x[2 + dj]), w23.x, aL2);              \
                        aH2 = fma4(cvt_hi(x[2 + dj]), w23.x, aH2);              \
                        aL3 = fma4(cvt_lo(x[3 + dj]), w23.y, aL3);              \
                        aH3 = fma4(cvt_hi(x[3 + dj]), w23.y, aH3);              \
                    }                                                           \
                }                                                               \
                uint4* op = pout + row * RSTR4;                                 \
                uint4 o0, o1, o2, o3;                                           \
                o0.x = pack2(aL0.x, aL0.y); o0.y = pack2(aL0.z, aL0.w);         \
                o0.z = pack2(aH0.x, aH0.y); o0.w = pack2(aH0.z, aH0.w);         \
                o1.x = pack2(aL1.x, aL1.y); o1.y = pack2(aL1.z, aL1.w);         \
                o1.z = pack2(aH1.x, aH1.y); o1.w = pack2(aH1.z, aH1.w);         \
                o2.x = pack2(aL2.x, aL2.y); o2.y = pack2(aL2.z, aL2.w);         \
                o2.z = pack2(aH2.x, aH2.y); o2.w = pack2(aH2.z, aH2.w);         \
                o3.x = pack2(aL3.x, aL3.y); o3.y = pack2(aL3.z, aL3.w);         \
                o3.z = pack2(aH3.x, aH3.y); o3.w = pack2(aH3.z, aH3.w);         \
                op[s]      = o0;                                                \
                op[32 + s] = o1;                                                \
                op[64 + s] = o2;                                                \
                op[96 + s] = o3;                                                \
            }                                                                   \
            __syncthreads();                                                    \
            uint4* tmp = pin; pin = pout; pout = tmp;                           \
        }

// ---- A: f32 source -> fp16-cell intermediate (UNCHANGED: measured ~35us) ----
__global__ __launch_bounds__(NTH, 1) void mp_fused5_a(const float* __restrict__ src,
                                                      uint4* __restrict__ dst16,
                                                      const uint2* __restrict__ nwh) {
    FUSED_PROLOGUE
    for (int ch = 0; ch < CGRP; ch += CSUB) {            // 2 chunks
        const float* sp = src + ((size_t)n * CC + cb + ch) * PLANE;
        for (int idx = t; idx < RROWS * WW; idx += NTH) {
            const int r  = idx >> 7;
            const int J  = idx & 127;
            const int gr = tr0 - HALO5 + r;
            uint4 v = zc;
            if (gr >= 0 && gr < HH) {
                const int o = gr * WW + J;
                v.x = pack2(sp[o],             sp[PLANE + o]);
                v.y = pack2(sp[2 * PLANE + o], sp[3 * PLANE + o]);
                v.z = pack2(sp[4 * PLANE + o], sp[5 * PLANE + o]);
                v.w = pack2(sp[6 * PLANE + o], sp[7 * PLANE + o]);
            }
            bufA[r * RSTR4 + PERM4(J)] = v;
        }
        __syncthreads();
        FUSED_STEPS
        uint4* dp16 = dst16 + ((size_t)n * (CC / 8) + ((cb + ch) >> 3)) * PLANE;
        for (int idx = t; idx < CORE * WW; idx += NTH) {
            const int r = idx >> 7;
            const int J = idx & 127;
            dp16[(tr0 + r) * WW + J] = pin[(r + HALO5) * RSTR4 + PERM4(J)];
        }
        __syncthreads();
    }
}

// ---- B: fp16-cell intermediate -> f32 dest (plain loads, unroll-1 anti-hoist) ----
__global__ __launch_bounds__(NTH, 1) void mp_fused5_b(const uint4* __restrict__ src16,
                                                      float* __restrict__ dst,
                                                      const uint2* __restrict__ nwh) {
    FUSED_PROLOGUE
#pragma unroll 1
    for (int ch = 0; ch < CGRP; ch += CSUB) {            // 2 chunks, NOT unrolled
        const uint4* sp16 = src16 + ((size_t)n * (CC / 8) + ((cb + ch) >> 3)) * PLANE;
        for (int idx = t; idx < RROWS * WW; idx += NTH) {
            const int r  = idx >> 7;
            const int J  = idx & 127;
            const int gr = tr0 - HALO5 + r;
            uint4 v = zc;
            if (gr >= 0 && gr < HH)
                v = sp16[gr * WW + J];                   // plain coalesced 16B load
            bufA[r * RSTR4 + PERM4(J)] = v;
        }
        __builtin_amdgcn_sched_barrier(0);               // no motion into step loop
        __syncthreads();
        FUSED_STEPS
        float* dp = dst + ((size_t)n * CC + cb + ch) * PLANE;
        for (int idx = t; idx < CORE * WW; idx += NTH) {
            const int r = idx >> 7;
            const int J = idx & 127;
            const uint4 v = pin[(r + HALO5) * RSTR4 + PERM4(J)];
            const float4 lo = cvt_lo(v);
            const float4 hi = cvt_hi(v);
            const int o = (tr0 + r) * WW + J;
            dp[o]             = lo.x;
            dp[PLANE + o]     = lo.y;
            dp[2 * PLANE + o] = lo.z;
            dp[3 * PLANE + o] = lo.w;
            dp[4 * PLANE + o] = hi.x;
            dp[5 * PLANE + o] = hi.y;
            dp[6 * PLANE + o] = hi.z;
            dp[7 * PLANE + o] = hi.w;
        }
        __syncthreads();
    }
}

extern "C" void kernel_launch(void* const* d_in, const int* in_sizes, int n_in,
                              void* d_out, int out_size, void* d_ws, size_t ws_size,
                              hipStream_t stream) {
    const float* input  = (const float*)d_in[0];
    const float* weight = (const float*)d_in[1];
    float* out = (float*)d_out;

    uint2* nwh = (uint2*)d_ws;                               // 2.36 MB fp16 weights
    uint4* B0  = (uint4*)((char*)d_ws + (size_t)NB * TAPS * PLANE * 2);  // 16.8 MB fp16 cells

    mp_norm_kernel<<<128, 256, 0, stream>>>(weight, nwh);
    mp_fused5_a<<<256, NTH, 0, stream>>>(input, B0, nwh);    // steps 1..5
    mp_fused5_b<<<256, NTH, 0, stream>>>(B0, out, nwh);      // steps 6..10
}

// Round 17
// 95.937 us; speedup vs baseline: 2.4952x; 2.4952x over previous
//
#include <hip/hip_runtime.h>
#include <hip/hip_fp16.h>

// MessagePassing: 10 iterations of 3x3 per-pixel-weighted smoothing.
//   input [8,64,128,128] f32, weight [8,9,128,128] f32 -> out [8,64,128,128] f32
// R17 = R15 (best: 92.5us) with b's B0 loads as inline-asm global_load_dwordx4.
// Evidence chain: any ORDINARY load shape for B0 in b lets the compiler
// restructure and spill the step-loop accumulators (R13/R14/R16: 471MB WRITE,
// ~202us), regardless of unroll-1/sched_barrier. volatile loads fix it (R15)
// but cost ~18us (L1 bypass + 16 serialized waitcnts). asm volatile loads are
// equally opaque/pinned but cached + pipelined: 4 loads in flight, ONE
// s_waitcnt vmcnt(0), then ds_writes. Step loop byte-identical to R15.
// Kill-check: if b's WRITE >> 40MB the spill returned -> ship R15 as final.

#define NB    8
#define CC    64
#define HH    128
#define WW    128
#define TAPS  9
#define PLANE (HH * WW)

#define CORE   16            // output tile rows per kernel
#define HALO5  5
#define RROWS  26            // CORE + 2*HALO5
#define RSTR4  129           // x-buffer row stride in cells (uint4)
#define NTH    832           // 26 rows * 32 strips, 13 waves
#define NSTEP  5
#define CGRP   16            // channels per block
#define CSUB   8             // channels per chunk (fp16 x8 in uint4 cell)
#define WROWS  24            // weight rows resident (region rows 1..24)
#define WCELLS (WROWS * TAPS * 32)   // half4 (uint2) cells = 6912 (55,296 B)

#define PERM4(J) ((((J) & 3) << 5) | ((J) >> 2))   // bijective on 0..127

typedef unsigned int u32x4 __attribute__((ext_vector_type(4)));

__device__ __forceinline__ float4 fma4(const float4 a, const float s, const float4 c) {
    return make_float4(fmaf(a.x, s, c.x), fmaf(a.y, s, c.y),
                       fmaf(a.z, s, c.z), fmaf(a.w, s, c.w));
}

__device__ __forceinline__ float4 cvt_lo(const uint4 v) {   // ch0-3
    const float2 a = __half22float2(*reinterpret_cast<const __half2*>(&v.x));
    const float2 b = __half22float2(*reinterpret_cast<const __half2*>(&v.y));
    return make_float4(a.x, a.y, b.x, b.y);
}
__device__ __forceinline__ float4 cvt_hi(const uint4 v) {   // ch4-7
    const float2 a = __half22float2(*reinterpret_cast<const __half2*>(&v.z));
    const float2 b = __half22float2(*reinterpret_cast<const __half2*>(&v.w));
    return make_float4(a.x, a.y, b.x, b.y);
}
__device__ __forceinline__ unsigned pack2(float a, float b) {
    __half2 h = __floats2half2_rn(a, b);
    return *reinterpret_cast<unsigned*>(&h);
}

// Normalize taps, store fp16: layout [n][9][128][32] uint2 (half4 cells).
__global__ __launch_bounds__(256) void mp_norm_kernel(const float* __restrict__ w,
                                                      uint2* __restrict__ nwh) {
    int tid = blockIdx.x * 256 + threadIdx.x;       // 32768 threads
    int wg = tid & 31;
    int h  = (tid >> 5) & 127;
    int n  = tid >> 12;
    int base = n * TAPS * PLANE + h * WW + wg * 4;
    float4 t[TAPS];
    float sx = 1e-5f, sy = 1e-5f, sz = 1e-5f, sw = 1e-5f;
#pragma unroll
    for (int k = 0; k < TAPS; ++k) {
        t[k] = *reinterpret_cast<const float4*>(w + base + k * PLANE);
        sx += t[k].x; sy += t[k].y; sz += t[k].z; sw += t[k].w;
    }
    float rx = 1.0f / sx, ry = 1.0f / sy, rz = 1.0f / sz, rw = 1.0f / sw;
#pragma unroll
    for (int k = 0; k < TAPS; ++k) {
        uint2 v;
        v.x = pack2(t[k].x * rx, t[k].y * ry);
        v.y = pack2(t[k].z * rz, t[k].w * rw);
        nwh[((n * TAPS + k) * HH + h) * 32 + wg] = v;
    }
}

// Shared pieces (macros so both kernels get byte-identical step loops without
// any shared template/function regalloc context).
#define FUSED_PROLOGUE                                                          \
    __shared__ uint4 bufA[RROWS * RSTR4];                                       \
    __shared__ uint4 bufB[RROWS * RSTR4];                                       \
    __shared__ uint2 wlds[WCELLS];                                              \
    const int bid = blockIdx.x;                                                 \
    const int n   = bid & 7;                                                    \
    const int ht  = (bid >> 3) & 7;                                             \
    const int cg  = bid >> 6;                                                   \
    const int tr0 = ht * CORE;                                                  \
    const int cb  = cg * CGRP;                                                  \
    const int t   = threadIdx.x;                                                \
    const int row = t >> 5;                                                     \
    const int s   = t & 31;                                                     \
    {                                                                           \
        const uint2* nwb = nwh + (size_t)n * TAPS * (PLANE / 4);                \
        for (int idx = t; idx < WCELLS; idx += NTH) {                           \
            const int wrow = idx / (TAPS * 32);                                 \
            const int rem  = idx - wrow * (TAPS * 32);                          \
            const int k    = rem >> 5;                                          \
            const int ss   = rem & 31;                                          \
            const int gr   = tr0 - (HALO5 - 1) + wrow;                          \
            uint2 v = make_uint2(0u, 0u);                                       \
            if (gr >= 0 && gr < HH)                                             \
                v = nwb[(k * HH + gr) * 32 + ss];                               \
            wlds[idx] = v;                                                      \
        }                                                                       \
    }                                                                           \
    const uint4 zc = make_uint4(0u, 0u, 0u, 0u);                                \
    const float4 z = make_float4(0.f, 0.f, 0.f, 0.f);

#define FUSED_STEPS                                                             \
        uint4* pin  = bufA;                                                     \
        uint4* pout = bufB;                                                     \
        for (int st = 0; st < NSTEP; ++st) {                                    \
            const int lo = st + 1;                                              \
            const int hi = 24 - st;                                             \
            if (row >= lo && row <= hi) {                                       \
                int wb = (row - 1) * (TAPS * 32) + s;                           \
                asm volatile("" : "+v"(wb));                                    \
                float4 aL0 = z, aL1 = z, aL2 = z, aL3 = z;                      \
                float4 aH0 = z, aH1 = z, aH2 = z, aH3 = z;                      \
                _Pragma("unroll")                                               \
                for (int di = 0; di < 3; ++di) {                                \
                    const uint4* rp = pin + (row - 1 + di) * RSTR4;             \
                    uint4 x[6];                                                 \
                    x[0] = (s > 0) ? rp[96 + s - 1] : zc;                       \
                    x[1] = rp[s];                                               \
                    x[2] = rp[32 + s];                                          \
                    x[3] = rp[64 + s];                                          \
                    x[4] = rp[96 + s];                                          \
                    x[5] = (s < 31) ? rp[s + 1] : zc;                           \
                    _Pragma("unroll")                                           \
                    for (int dj = 0; dj < 3; ++dj) {                            \
                        const int k = di * 3 + dj;                              \
                        const uint2 wv = wlds[wb + k * 32];                     \
                        const float2 w01 = __half22float2(*reinterpret_cast<const __half2*>(&wv.x)); \
                        const float2 w23 = __half22float2(*reinterpret_cast<const __half2*>(&wv.y)); \
                        aL0 = fma4(cvt_lo(x[0 + dj]), w01.x, aL0);              \
                        aH0 = fma4(cvt_hi(x[0 + dj]), w01.x, aH0);              \
                        aL1 = fma4(cvt_lo(x[1 + dj]), w01.y, aL1);              \
                        aH1 = fma4(cvt_hi(x[1 + dj]), w01.y, aH1);              \
                        aL2 = fma4(cvt_lo(x[2 + dj]), w23.x, aL2);              \
                        aH2 = fma4(cvt_hi(x[2 + dj]), w23.x, aH2);              \
                        aL3 = fma4(cvt_lo(x[3 + dj]), w23.y, aL3);              \
                        aH3 = fma4(cvt_hi(x[3 + dj]), w23.y, aH3);              \
                    }                                                           \
                }                                                               \
                uint4* op = pout + row * RSTR4;                                 \
                uint4 o0, o1, o2, o3;                                           \
                o0.x = pack2(aL0.x, aL0.y); o0.y = pack2(aL0.z, aL0.w);         \
                o0.z = pack2(aH0.x, aH0.y); o0.w = pack2(aH0.z, aH0.w);         \
                o1.x = pack2(aL1.x, aL1.y); o1.y = pack2(aL1.z, aL1.w);         \
                o1.z = pack2(aH1.x, aH1.y); o1.w = pack2(aH1.z, aH1.w);         \
                o2.x = pack2(aL2.x, aL2.y); o2.y = pack2(aL2.z, aL2.w);         \
                o2.z = pack2(aH2.x, aH2.y); o2.w = pack2(aH2.z, aH2.w);         \
                o3.x = pack2(aL3.x, aL3.y); o3.y = pack2(aL3.z, aL3.w);         \
                o3.z = pack2(aH3.x, aH3.y); o3.w = pack2(aH3.z, aH3.w);         \
                op[s]      = o0;                                                \
                op[32 + s] = o1;                                                \
                op[64 + s] = o2;                                                \
                op[96 + s] = o3;                                                \
            }                                                                   \
            __syncthreads();                                                    \
            uint4* tmp = pin; pin = pout; pout = tmp;                           \
        }

// ---- A: f32 source -> fp16-cell intermediate (UNCHANGED: measured ~35us) ----
__global__ __launch_bounds__(NTH, 1) void mp_fused5_a(const float* __restrict__ src,
                                                      uint4* __restrict__ dst16,
                                                      const uint2* __restrict__ nwh) {
    FUSED_PROLOGUE
    for (int ch = 0; ch < CGRP; ch += CSUB) {            // 2 chunks
        const float* sp = src + ((size_t)n * CC + cb + ch) * PLANE;
        for (int idx = t; idx < RROWS * WW; idx += NTH) {
            const int r  = idx >> 7;
            const int J  = idx & 127;
            const int gr = tr0 - HALO5 + r;
            uint4 v = zc;
            if (gr >= 0 && gr < HH) {
                const int o = gr * WW + J;
                v.x = pack2(sp[o],             sp[PLANE + o]);
                v.y = pack2(sp[2 * PLANE + o], sp[3 * PLANE + o]);
                v.z = pack2(sp[4 * PLANE + o], sp[5 * PLANE + o]);
                v.w = pack2(sp[6 * PLANE + o], sp[7 * PLANE + o]);
            }
            bufA[r * RSTR4 + PERM4(J)] = v;
        }
        __syncthreads();
        FUSED_STEPS
        uint4* dp16 = dst16 + ((size_t)n * (CC / 8) + ((cb + ch) >> 3)) * PLANE;
        for (int idx = t; idx < CORE * WW; idx += NTH) {
            const int r = idx >> 7;
            const int J = idx & 127;
            dp16[(tr0 + r) * WW + J] = pin[(r + HALO5) * RSTR4 + PERM4(J)];
        }
        __syncthreads();
    }
}

// ---- B: fp16-cell intermediate -> f32 dest (asm-pinned, pipelined B0 loads) ----
__global__ __launch_bounds__(NTH, 1) void mp_fused5_b(const uint4* __restrict__ src16,
                                                      float* __restrict__ dst,
                                                      const uint2* __restrict__ nwh) {
    FUSED_PROLOGUE
#pragma unroll 1
    for (int ch = 0; ch < CGRP; ch += CSUB) {            // 2 chunks, NOT unrolled
        const uint4* sp16 = src16 + ((size_t)n * (CC / 8) + ((cb + ch) >> 3)) * PLANE;

        // Issue all 4 region loads via opaque asm (unhoistable, but cached &
        // fully in flight), then ONE waitcnt, then commit to LDS.
        u32x4 vv0, vv1, vv2, vv3;
        {
            const int i0 = t, i1 = t + NTH, i2 = t + 2 * NTH, i3 = t + 3 * NTH;
            const int g0 = tr0 - HALO5 + (i0 >> 7);
            const int g1 = tr0 - HALO5 + (i1 >> 7);
            const int g2 = tr0 - HALO5 + (i2 >> 7);
            const int g3 = tr0 - HALO5 + (i3 >> 7);
            const uint4* a0 = sp16 + min(max(g0, 0), HH - 1) * WW + (i0 & 127);
            const uint4* a1 = sp16 + min(max(g1, 0), HH - 1) * WW + (i1 & 127);
            const uint4* a2 = sp16 + min(max(g2, 0), HH - 1) * WW + (i2 & 127);
            const uint4* a3 = sp16 + min(max(g3, 0), HH - 1) * WW + (i3 & 127);
            asm volatile("global_load_dwordx4 %0, %1, off" : "=v"(vv0) : "v"(a0));
            asm volatile("global_load_dwordx4 %0, %1, off" : "=v"(vv1) : "v"(a1));
            asm volatile("global_load_dwordx4 %0, %1, off" : "=v"(vv2) : "v"(a2));
            asm volatile("global_load_dwordx4 %0, %1, off" : "=v"(vv3) : "v"(a3));
            asm volatile("s_waitcnt vmcnt(0)" ::: "memory");
            __builtin_amdgcn_sched_barrier(0);
            const bool k0 = (g0 >= 0 && g0 < HH);
            const bool k1 = (g1 >= 0 && g1 < HH);
            const bool k2 = (g2 >= 0 && g2 < HH);
            const bool k3 = (g3 >= 0 && g3 < HH);
            bufA[(i0 >> 7) * RSTR4 + PERM4(i0 & 127)] =
                k0 ? make_uint4(vv0.x, vv0.y, vv0.z, vv0.w) : zc;
            bufA[(i1 >> 7) * RSTR4 + PERM4(i1 & 127)] =
                k1 ? make_uint4(vv1.x, vv1.y, vv1.z, vv1.w) : zc;
            bufA[(i2 >> 7) * RSTR4 + PERM4(i2 & 127)] =
                k2 ? make_uint4(vv2.x, vv2.y, vv2.z, vv2.w) : zc;
            bufA[(i3 >> 7) * RSTR4 + PERM4(i3 & 127)] =
                k3 ? make_uint4(vv3.x, vv3.y, vv3.z, vv3.w) : zc;
        }
        __builtin_amdgcn_sched_barrier(0);
        __syncthreads();
        FUSED_STEPS
        float* dp = dst + ((size_t)n * CC + cb + ch) * PLANE;
        for (int idx = t; idx < CORE * WW; idx += NTH) {
            const int r = idx >> 7;
            const int J = idx & 127;
            const uint4 v = pin[(r + HALO5) * RSTR4 + PERM4(J)];
            const float4 lo = cvt_lo(v);
            const float4 hi = cvt_hi(v);
            const int o = (tr0 + r) * WW + J;
            dp[o]             = lo.x;
            dp[PLANE + o]     = lo.y;
            dp[2 * PLANE + o] = lo.z;
            dp[3 * PLANE + o] = lo.w;
            dp[4 * PLANE + o] = hi.x;
            dp[5 * PLANE + o] = hi.y;
            dp[6 * PLANE + o] = hi.z;
            dp[7 * PLANE + o] = hi.w;
        }
        __syncthreads();
    }
}

extern "C" void kernel_launch(void* const* d_in, const int* in_sizes, int n_in,
                              void* d_out, int out_size, void* d_ws, size_t ws_size,
                              hipStream_t stream) {
    const float* input  = (const float*)d_in[0];
    const float* weight = (const float*)d_in[1];
    float* out = (float*)d_out;

    uint2* nwh = (uint2*)d_ws;                               // 2.36 MB fp16 weights
    uint4* B0  = (uint4*)((char*)d_ws + (size_t)NB * TAPS * PLANE * 2);  // 16.8 MB fp16 cells

    mp_norm_kernel<<<128, 256, 0, stream>>>(weight, nwh);
    mp_fused5_a<<<256, NTH, 0, stream>>>(input, B0, nwh);    // steps 1..5
    mp_fused5_b<<<256, NTH, 0, stream>>>(B0, out, nwh);      // steps 6..10
}

// Round 18
// 88.762 us; speedup vs baseline: 2.6969x; 1.0808x over previous
//
#include <hip/hip_runtime.h>
#include <hip/hip_fp16.h>

// MessagePassing: 10 iterations of 3x3 per-pixel-weighted smoothing.
//   input [8,64,128,128] f32, weight [8,9,128,128] f32 -> out [8,64,128,128] f32
// R18 = R15 (92.5us best) with b's 16 volatile dword loads replaced by 4
// volatile ext-vector (u32x4) loads -> single global_load_dwordx4 each.
// Load-shape scoreboard for b (step loop identical in all):
//   ordinary uint4          -> full acc spill, 202us   (R14/R16)
//   inline-asm dwordx4      -> partial spill,  58.8us  (R17: 16 "=v" outputs)
//   volatile dword x16      -> clean,          53.5us  (R15)
// Volatile = opaque to LICM/scheduler AND zero extra register lifetime (value
// dies at its ds_write). ext-vector volatile keeps both properties at 1/4 the
// instruction count and full memory-level parallelism.
// Kill-check: if b's WRITE >> 40MB -> ship R15 as final.

#define NB    8
#define CC    64
#define HH    128
#define WW    128
#define TAPS  9
#define PLANE (HH * WW)

#define CORE   16            // output tile rows per kernel
#define HALO5  5
#define RROWS  26            // CORE + 2*HALO5
#define RSTR4  129           // x-buffer row stride in cells (uint4)
#define NTH    832           // 26 rows * 32 strips, 13 waves
#define NSTEP  5
#define CGRP   16            // channels per block
#define CSUB   8             // channels per chunk (fp16 x8 in uint4 cell)
#define WROWS  24            // weight rows resident (region rows 1..24)
#define WCELLS (WROWS * TAPS * 32)   // half4 (uint2) cells = 6912 (55,296 B)

#define PERM4(J) ((((J) & 3) << 5) | ((J) >> 2))   // bijective on 0..127

typedef unsigned int u32x4 __attribute__((ext_vector_type(4)));

__device__ __forceinline__ float4 fma4(const float4 a, const float s, const float4 c) {
    return make_float4(fmaf(a.x, s, c.x), fmaf(a.y, s, c.y),
                       fmaf(a.z, s, c.z), fmaf(a.w, s, c.w));
}

__device__ __forceinline__ float4 cvt_lo(const uint4 v) {   // ch0-3
    const float2 a = __half22float2(*reinterpret_cast<const __half2*>(&v.x));
    const float2 b = __half22float2(*reinterpret_cast<const __half2*>(&v.y));
    return make_float4(a.x, a.y, b.x, b.y);
}
__device__ __forceinline__ float4 cvt_hi(const uint4 v) {   // ch4-7
    const float2 a = __half22float2(*reinterpret_cast<const __half2*>(&v.z));
    const float2 b = __half22float2(*reinterpret_cast<const __half2*>(&v.w));
    return make_float4(a.x, a.y, b.x, b.y);
}
__device__ __forceinline__ unsigned pack2(float a, float b) {
    __half2 h = __floats2half2_rn(a, b);
    return *reinterpret_cast<unsigned*>(&h);
}

// Normalize taps, store fp16: layout [n][9][128][32] uint2 (half4 cells).
__global__ __launch_bounds__(256) void mp_norm_kernel(const float* __restrict__ w,
                                                      uint2* __restrict__ nwh) {
    int tid = blockIdx.x * 256 + threadIdx.x;       // 32768 threads
    int wg = tid & 31;
    int h  = (tid >> 5) & 127;
    int n  = tid >> 12;
    int base = n * TAPS * PLANE + h * WW + wg * 4;
    float4 t[TAPS];
    float sx = 1e-5f, sy = 1e-5f, sz = 1e-5f, sw = 1e-5f;
#pragma unroll
    for (int k = 0; k < TAPS; ++k) {
        t[k] = *reinterpret_cast<const float4*>(w + base + k * PLANE);
        sx += t[k].x; sy += t[k].y; sz += t[k].z; sw += t[k].w;
    }
    float rx = 1.0f / sx, ry = 1.0f / sy, rz = 1.0f / sz, rw = 1.0f / sw;
#pragma unroll
    for (int k = 0; k < TAPS; ++k) {
        uint2 v;
        v.x = pack2(t[k].x * rx, t[k].y * ry);
        v.y = pack2(t[k].z * rz, t[k].w * rw);
        nwh[((n * TAPS + k) * HH + h) * 32 + wg] = v;
    }
}

// Shared pieces (macros so both kernels get byte-identical step loops without
// any shared template/function regalloc context).
#define FUSED_PROLOGUE                                                          \
    __shared__ uint4 bufA[RROWS * RSTR4];                                       \
    __shared__ uint4 bufB[RROWS * RSTR4];                                       \
    __shared__ uint2 wlds[WCELLS];                                              \
    const int bid = blockIdx.x;                                                 \
    const int n   = bid & 7;                                                    \
    const int ht  = (bid >> 3) & 7;                                             \
    const int cg  = bid >> 6;                                                   \
    const int tr0 = ht * CORE;                                                  \
    const int cb  = cg * CGRP;                                                  \
    const int t   = threadIdx.x;                                                \
    const int row = t >> 5;                                                     \
    const int s   = t & 31;                                                     \
    {                                                                           \
        const uint2* nwb = nwh + (size_t)n * TAPS * (PLANE / 4);                \
        for (int idx = t; idx < WCELLS; idx += NTH) {                           \
            const int wrow = idx / (TAPS * 32);                                 \
            const int rem  = idx - wrow * (TAPS * 32);                          \
            const int k    = rem >> 5;                                          \
            const int ss   = rem & 31;                                          \
            const int gr   = tr0 - (HALO5 - 1) + wrow;                          \
            uint2 v = make_uint2(0u, 0u);                                       \
            if (gr >= 0 && gr < HH)                                             \
                v = nwb[(k * HH + gr) * 32 + ss];                               \
            wlds[idx] = v;                                                      \
        }                                                                       \
    }                                                                           \
    const uint4 zc = make_uint4(0u, 0u, 0u, 0u);                                \
    const float4 z = make_float4(0.f, 0.f, 0.f, 0.f);

#define FUSED_STEPS                                                             \
        uint4* pin  = bufA;                                                     \
        uint4* pout = bufB;                                                     \
        for (int st = 0; st < NSTEP; ++st) {                                    \
            const int lo = st + 1;                                              \
            const int hi = 24 - st;                                             \
            if (row >= lo && row <= hi) {                                       \
                int wb = (row - 1) * (TAPS * 32) + s;                           \
                asm volatile("" : "+v"(wb));                                    \
                float4 aL0 = z, aL1 = z, aL2 = z, aL3 = z;                      \
                float4 aH0 = z, aH1 = z, aH2 = z, aH3 = z;                      \
                _Pragma("unroll")                                               \
                for (int di = 0; di < 3; ++di) {                                \
                    const uint4* rp = pin + (row - 1 + di) * RSTR4;             \
                    uint4 x[6];                                                 \
                    x[0] = (s > 0) ? rp[96 + s - 1] : zc;                       \
                    x[1] = rp[s];                                               \
                    x[2] = rp[32 + s];                                          \
                    x[3] = rp[64 + s];                                          \
                    x[4] = rp[96 + s];                                          \
                    x[5] = (s < 31) ? rp[s + 1] : zc;                           \
                    _Pragma("unroll")                                           \
                    for (int dj = 0; dj < 3; ++dj) {                            \
                        const int k = di * 3 + dj;                              \
                        const uint2 wv = wlds[wb + k * 32];                     \
                        const float2 w01 = __half22float2(*reinterpret_cast<const __half2*>(&wv.x)); \
                        const float2 w23 = __half22float2(*reinterpret_cast<const __half2*>(&wv.y)); \
                        aL0 = fma4(cvt_lo(x[0 + dj]), w01.x, aL0);              \
                        aH0 = fma4(cvt_hi(x[0 + dj]), w01.x, aH0);              \
                        aL1 = fma4(cvt_lo(x[1 + dj]), w01.y, aL1);              \
                        aH1 = fma4(cvt_hi(x[1 + dj]), w01.y, aH1);              \
                        aL2 = fma4(cvt_lo(x[2 + dj]), w23.x, aL2);              \
                        aH2 = fma4(cvt_hi(x[2 + dj]), w23.x, aH2);              \
                        aL3 = fma4(cvt_lo(x[3 + dj]), w23.y, aL3);              \
                        aH3 = fma4(cvt_hi(x[3 + dj]), w23.y, aH3);              \
                    }                                                           \
                }                                                               \
                uint4* op = pout + row * RSTR4;                                 \
                uint4 o0, o1, o2, o3;                                           \
                o0.x = pack2(aL0.x, aL0.y); o0.y = pack2(aL0.z, aL0.w);         \
                o0.z = pack2(aH0.x, aH0.y); o0.w = pack2(aH0.z, aH0.w);         \
                o1.x = pack2(aL1.x, aL1.y); o1.y = pack2(aL1.z, aL1.w);         \
                o1.z = pack2(aH1.x, aH1.y); o1.w = pack2(aH1.z, aH1.w);         \
                o2.x = pack2(aL2.x, aL2.y); o2.y = pack2(aL2.z, aL2.w);         \
                o2.z = pack2(aH2.x, aH2.y); o2.w = pack2(aH2.z, aH2.w);         \
                o3.x = pack2(aL3.x, aL3.y); o3.y = pack2(aL3.z, aL3.w);         \
                o3.z = pack2(aH3.x, aH3.y); o3.w = pack2(aH3.z, aH3.w);         \
                op[s]      = o0;                                                \
                op[32 + s] = o1;                                                \
                op[64 + s] = o2;                                                \
                op[96 + s] = o3;                                                \
            }                                                                   \
            __syncthreads();                                                    \
            uint4* tmp = pin; pin = pout; pout = tmp;                           \
        }

// ---- A: f32 source -> fp16-cell intermediate (UNCHANGED: measured ~35us) ----
__global__ __launch_bounds__(NTH, 1) void mp_fused5_a(const float* __restrict__ src,
                                                      uint4* __restrict__ dst16,
                                                      const uint2* __restrict__ nwh) {
    FUSED_PROLOGUE
    for (int ch = 0; ch < CGRP; ch += CSUB) {            // 2 chunks
        const float* sp = src + ((size_t)n * CC + cb + ch) * PLANE;
        for (int idx = t; idx < RROWS * WW; idx += NTH) {
            const int r  = idx >> 7;
            const int J  = idx & 127;
            const int gr = tr0 - HALO5 + r;
            uint4 v = zc;
            if (gr >= 0 && gr < HH) {
                const int o = gr * WW + J;
                v.x = pack2(sp[o],             sp[PLANE + o]);
                v.y = pack2(sp[2 * PLANE + o], sp[3 * PLANE + o]);
                v.z = pack2(sp[4 * PLANE + o], sp[5 * PLANE + o]);
                v.w = pack2(sp[6 * PLANE + o], sp[7 * PLANE + o]);
            }
            bufA[r * RSTR4 + PERM4(J)] = v;
        }
        __syncthreads();
        FUSED_STEPS
        uint4* dp16 = dst16 + ((size_t)n * (CC / 8) + ((cb + ch) >> 3)) * PLANE;
        for (int idx = t; idx < CORE * WW; idx += NTH) {
            const int r = idx >> 7;
            const int J = idx & 127;
            dp16[(tr0 + r) * WW + J] = pin[(r + HALO5) * RSTR4 + PERM4(J)];
        }
        __syncthreads();
    }
}

// ---- B: fp16-cell intermediate -> f32 dest (volatile dwordx4 loads) ----
__global__ __launch_bounds__(NTH, 1) void mp_fused5_b(const uint4* __restrict__ src16,
                                                      float* __restrict__ dst,
                                                      const uint2* __restrict__ nwh) {
    FUSED_PROLOGUE
#pragma unroll 1
    for (int ch = 0; ch < CGRP; ch += CSUB) {            // 2 chunks, NOT unrolled
        // Volatile ext-vector loads: one global_load_dwordx4 per cell,
        // program-order pinned (anti-spill, proven R15), value dies at its
        // ds_write -> no added register lifetime.
        const volatile u32x4* sp16v =
            (const volatile u32x4*)(src16 + ((size_t)n * (CC / 8) + ((cb + ch) >> 3)) * PLANE);
        for (int idx = t; idx < RROWS * WW; idx += NTH) {
            const int r  = idx >> 7;
            const int J  = idx & 127;
            const int gr = tr0 - HALO5 + r;
            uint4 v = zc;
            if (gr >= 0 && gr < HH) {
                const u32x4 w = sp16v[gr * WW + J];
                v = make_uint4(w.x, w.y, w.z, w.w);
            }
            bufA[r * RSTR4 + PERM4(J)] = v;
        }
        __syncthreads();
        FUSED_STEPS
        float* dp = dst + ((size_t)n * CC + cb + ch) * PLANE;
        for (int idx = t; idx < CORE * WW; idx += NTH) {
            const int r = idx >> 7;
            const int J = idx & 127;
            const uint4 v = pin[(r + HALO5) * RSTR4 + PERM4(J)];
            const float4 lo = cvt_lo(v);
            const float4 hi = cvt_hi(v);
            const int o = (tr0 + r) * WW + J;
            dp[o]             = lo.x;
            dp[PLANE + o]     = lo.y;
            dp[2 * PLANE + o] = lo.z;
            dp[3 * PLANE + o] = lo.w;
            dp[4 * PLANE + o] = hi.x;
            dp[5 * PLANE + o] = hi.y;
            dp[6 * PLANE + o] = hi.z;
            dp[7 * PLANE + o] = hi.w;
        }
        __syncthreads();
    }
}

extern "C" void kernel_launch(void* const* d_in, const int* in_sizes, int n_in,
                              void* d_out, int out_size, void* d_ws, size_t ws_size,
                              hipStream_t stream) {
    const float* input  = (const float*)d_in[0];
    const float* weight = (const float*)d_in[1];
    float* out = (float*)d_out;

    uint2* nwh = (uint2*)d_ws;                               // 2.36 MB fp16 weights
    uint4* B0  = (uint4*)((char*)d_ws + (size_t)NB * TAPS * PLANE * 2);  // 16.8 MB fp16 cells

    mp_norm_kernel<<<128, 256, 0, stream>>>(weight, nwh);
    mp_fused5_a<<<256, NTH, 0, stream>>>(input, B0, nwh);    // steps 1..5
    mp_fused5_b<<<256, NTH, 0, stream>>>(B0, out, nwh);      // steps 6..10
}